// Round 1
// baseline (446.396 us; speedup 1.0000x reference)
//
#include <hip/hip_runtime.h>
#include <hip/hip_bf16.h>
#include <math.h>

#define B_ 32
#define S_ 64
#define T_ 256
#define L_ 8
#define D_ 128
#define H_ 128

typedef __attribute__((ext_vector_type(8))) short short8;
typedef __attribute__((ext_vector_type(4))) float float4v;

// ---------------------------------------------------------------------------
// Stage A: build K_l (SE kernel + 1e-4 jitter) and Cholesky-factor it.
// One block per latent l (8 blocks x 256 threads). Blocked left-looking,
// panel of 32 columns held in per-thread registers (thread = row), column
// broadcast through LDS, GEMM update against finalized panels read from L2.
// ---------------------------------------------------------------------------
__global__ __launch_bounds__(256) void k_cholesky(
    const float* __restrict__ times, const float* __restrict__ log_taus,
    float* __restrict__ Lc /* [L][T][T], pre-zeroed */)
{
  __shared__ float times_s[T_];
  __shared__ float colbuf[32][32];   // colbuf[c][i]: published raw column values
  __shared__ float LsT[32][36];      // LsT[kk][c] = L[col0+c][k0+kk]
  const int l = blockIdx.x;
  const int tid = threadIdx.x;
  float* Lg = Lc + (size_t)l * T_ * T_;

  for (int i = tid; i < T_; i += 256) times_s[i] = times[i];
  __syncthreads();

  const float tau = expf(log_taus[l]);
  const float inv2tau2 = 0.5f / (tau * tau);
  const float sig2 = 0.999f * 0.999f;

  float row[32];

  for (int p = 0; p < 8; ++p) {
    const int col0 = p * 32;
    const int r = col0 + tid;
    const bool active = (r < T_);

    // init panel with K values
    if (active) {
      const float tr = times_s[r];
#pragma unroll
      for (int c = 0; c < 32; ++c) {
        float dt = tr - times_s[col0 + c];
        float v = sig2 * expf(-dt * dt * inv2tau2);
        if (r == col0 + c) v += 1e-4f;
        row[c] = v;
      }
    }

    // left-looking GEMM update: row[c] -= sum_{k<col0} L[r][k] * L[col0+c][k]
    for (int kb = 0; kb < p; ++kb) {
      const int k0 = kb * 32;
      {
        int c = tid >> 3, kq = tid & 7;
        const float4v v = *(const float4v*)&Lg[(size_t)(col0 + c) * T_ + k0 + kq * 4];
#pragma unroll
        for (int j = 0; j < 4; ++j) LsT[kq * 4 + j][c] = v[j];
      }
      __syncthreads();
      if (active) {
        const float* rowp = &Lg[(size_t)r * T_ + k0];
        float4v lr[8];
#pragma unroll
        for (int q = 0; q < 8; ++q) lr[q] = *(const float4v*)&rowp[q * 4];
#pragma unroll
        for (int kk = 0; kk < 32; ++kk) {
          float lrv = lr[kk >> 2][kk & 3];
#pragma unroll
          for (int c4 = 0; c4 < 8; ++c4) {
            float4v ls = *(const float4v*)&LsT[kk][c4 * 4];
#pragma unroll
            for (int j = 0; j < 4; ++j) row[c4 * 4 + j] -= lrv * ls[j];
          }
        }
      }
      __syncthreads();
    }

    // panel factorization: 32 fully-unrolled column steps (static reg indices)
#pragma unroll
    for (int c = 0; c < 32; ++c) {
      if (tid >= c && tid < 32) colbuf[c][tid] = row[c];
      __syncthreads();
      float cv[32];
#pragma unroll
      for (int c4 = 0; c4 < 8; ++c4) {
        float4v v = *(const float4v*)&colbuf[c][c4 * 4];
#pragma unroll
        for (int j = 0; j < 4; ++j) cv[c4 * 4 + j] = v[j];
      }
      const float pc = cv[c];
      const float dq = sqrtf(pc);
      const float inv = 1.0f / dq;
      const float inv2 = inv * inv;
      if (active && r > col0 + c) {
        const float raw = row[c];
        row[c] = raw * inv;                 // final L[r][col0+c]
        const float f = raw * inv2;
#pragma unroll
        for (int c2 = c + 1; c2 < 32; ++c2) row[c2] -= f * cv[c2];
      } else if (active && r == col0 + c) {
        row[c] = dq;                        // diagonal
      }
    }

    // writeback (zero entries above the diagonal inside panel)
    if (active) {
#pragma unroll
      for (int c4 = 0; c4 < 8; ++c4) {
        float4v v;
#pragma unroll
        for (int j = 0; j < 4; ++j) {
          int c = c4 * 4 + j;
          v[j] = (col0 + c <= r) ? row[c] : 0.0f;
        }
        *(float4v*)&Lg[(size_t)r * T_ + col0 + c4 * 4] = v;
      }
    }
    __threadfence();
    __syncthreads();
  }
}

// ---------------------------------------------------------------------------
// Stage B: z[bs, l, u] = sum_t Lc[l][u][t] * eps[bs, l, t]
// 8 GEMMs M=2048, N=256, K<=u0+64 (lower-triangular skip). FP32 tiled.
// Z stored with the same layout as eps: [BS][L][T].
// ---------------------------------------------------------------------------
__global__ __launch_bounds__(256) void k_zgemm(
    const float* __restrict__ eps, const float* __restrict__ Lc,
    float* __restrict__ Z)
{
  __shared__ float Ea[16][68];
  __shared__ float Lb[16][68];
  const int bi = blockIdx.x;
  const int l = bi & 7;
  const int rest = bi >> 3;
  const int u0 = (rest & 3) * 64;
  const int bs0 = (rest >> 2) * 64;
  const int tid = threadIdx.x;
  const int tx = tid & 15, ty = tid >> 4;
  const int lrow = tid >> 2, lkq = tid & 3;

  float acc[4][4] = {};
  const int kend = u0 + 64;   // t <= u only (L is lower-triangular)
  for (int k0 = 0; k0 < kend; k0 += 16) {
    {
      float4v v = *(const float4v*)&eps[((size_t)(bs0 + lrow) * 8 + l) * T_ + k0 + lkq * 4];
#pragma unroll
      for (int j = 0; j < 4; ++j) Ea[lkq * 4 + j][lrow] = v[j];
      float4v w = *(const float4v*)&Lc[((size_t)l * T_ + u0 + lrow) * T_ + k0 + lkq * 4];
#pragma unroll
      for (int j = 0; j < 4; ++j) Lb[lkq * 4 + j][lrow] = w[j];
    }
    __syncthreads();
#pragma unroll
    for (int kk = 0; kk < 16; ++kk) {
      float4v a = *(const float4v*)&Ea[kk][ty * 4];
      float4v bv = *(const float4v*)&Lb[kk][tx * 4];
#pragma unroll
      for (int i = 0; i < 4; ++i)
#pragma unroll
        for (int j = 0; j < 4; ++j) acc[i][j] += a[i] * bv[j];
    }
    __syncthreads();
  }
#pragma unroll
  for (int i = 0; i < 4; ++i) {
    float4v v;
#pragma unroll
    for (int j = 0; j < 4; ++j) v[j] = acc[i][j];
    *(float4v*)&Z[((size_t)(bs0 + ty * 4 + i) * 8 + l) * T_ + u0 + tx * 4] = v;
  }
}

// ---------------------------------------------------------------------------
// W2 -> bf16 transposed [D][H] so MFMA B-fragments are contiguous loads.
// ---------------------------------------------------------------------------
__global__ __launch_bounds__(256) void k_w2t(
    const float* __restrict__ W2, __hip_bfloat16* __restrict__ W2T)
{
  int idx = blockIdx.x * 256 + threadIdx.x;   // 16384
  int h = idx >> 7, d = idx & 127;
  W2T[(size_t)d * 128 + h] = __float2bfloat16(W2[(size_t)h * 128 + d]);
}

// ---------------------------------------------------------------------------
// Stage C/D/E/F fused: one block per (b,s). h = tanh(Z W1 + b1) in LDS (bf16),
// mu = h W2 via mfma_f32_16x16x32_bf16 with B-frags (W2T) held in registers,
// epilogue computes sum_{t,d} (X-mu)^2 * invr, single write of ll[bs].
// ll[bs] = -0.5*Q - T*log_norm.
// ---------------------------------------------------------------------------
__global__ __launch_bounds__(256) void k_decode(
    const float* __restrict__ X, const float* __restrict__ Z,
    const float* __restrict__ W1, const float* __restrict__ b1,
    const __hip_bfloat16* __restrict__ W2T, const float* __restrict__ b2,
    const float* __restrict__ log_R, float* __restrict__ ll)
{
  __shared__ float Zt[T_][9];                  // z for all 256 t of this (b,s)
  __shared__ float W1s[L_][H_];
  __shared__ float b1s[H_];
  __shared__ __hip_bfloat16 hS[128][136];      // half (128 t) of h, padded rows
  __shared__ float redbuf[4];
  __shared__ float sLR;

  const int bs = blockIdx.x;
  const int b = bs >> 6;
  const int tid = threadIdx.x;
  const int w = tid >> 6, lane = tid & 63;
  const int n = lane & 15, q = lane >> 4;

  // stage Z (coalesced), W1, b1
  for (int i = 0; i < 8; ++i) {
    int idx = tid + 256 * i;
    int t = idx & 255, li = idx >> 8;
    Zt[t][li] = Z[((size_t)bs * 8 + li) * T_ + t];
  }
  for (int i = tid; i < L_ * H_; i += 256) W1s[i >> 7][i & 127] = W1[i];
  if (tid < H_) b1s[tid] = b1[tid];
  if (tid < 64) {   // sum(log_R) via wave 0
    float v = log_R[tid] + log_R[tid + 64];
#pragma unroll
    for (int off = 32; off >= 1; off >>= 1) v += __shfl_xor(v, off);
    if (tid == 0) sLR = v;
  }

  // per-lane column constants (d = nt*16 + n fixed per lane)
  float invr_l[8], b2_l[8];
#pragma unroll
  for (int nt = 0; nt < 8; ++nt) {
    int d = nt * 16 + n;
    invr_l[nt] = expf(-log_R[d]);
    b2_l[nt] = b2[d];
  }

  // B-fragments: W2[k][d], lane holds B[k = q*8+j][n]; contiguous in W2T[d][k]
  short8 bfr[8][4];
#pragma unroll
  for (int nt = 0; nt < 8; ++nt)
#pragma unroll
    for (int ks = 0; ks < 4; ++ks)
      bfr[nt][ks] = *(const short8*)&W2T[(size_t)(nt * 16 + n) * 128 + ks * 32 + q * 8];

  float qsum = 0.0f;

  for (int half = 0; half < 2; ++half) {
    const int th = half * 128;
    __syncthreads();   // staging ready / previous half's hS consumed
    // h-compute: 128 t x 128 h over 256 threads
    {
      const int tl = tid & 127;
      const int hh0 = (tid >> 7) * 64;
      float z[8];
#pragma unroll
      for (int li = 0; li < 8; ++li) z[li] = Zt[th + tl][li];
      for (int hh = 0; hh < 64; ++hh) {
        int h = hh0 + hh;
        float a = b1s[h];
#pragma unroll
        for (int li = 0; li < 8; ++li) a += z[li] * W1s[li][h];
        float xc = fminf(fmaxf(a, -10.f), 10.f);
        float e = __expf(2.f * xc);
        float hv = 1.f - 2.f / (e + 1.f);    // tanh
        hS[tl][h] = __float2bfloat16(hv);
      }
    }
    __syncthreads();
    // MFMA: wave w owns t-rows [w*32, w*32+32) of this half
#pragma unroll
    for (int mt = 0; mt < 2; ++mt) {
      const int m0 = w * 32 + mt * 16;
      short8 af[4];
#pragma unroll
      for (int ks = 0; ks < 4; ++ks)
        af[ks] = *(const short8*)&hS[m0 + n][ks * 32 + q * 8];
#pragma unroll
      for (int nt = 0; nt < 8; ++nt) {
        float4v acc = {0.f, 0.f, 0.f, 0.f};
#pragma unroll
        for (int ks = 0; ks < 4; ++ks)
          acc = __builtin_amdgcn_mfma_f32_16x16x32_bf16(af[ks], bfr[nt][ks], acc, 0, 0, 0);
        const int d = nt * 16 + n;
#pragma unroll
        for (int r = 0; r < 4; ++r) {
          int t = th + m0 + q * 4 + r;       // C/D: row = q*4+reg, col = lane&15
          float mu = acc[r] + b2_l[nt];
          float xv = X[((size_t)b * T_ + t) * D_ + d];
          float diff = xv - mu;
          qsum += diff * diff * invr_l[nt];
        }
      }
    }
  }

  // block reduction of qsum -> ll[bs]
#pragma unroll
  for (int off = 32; off >= 1; off >>= 1) qsum += __shfl_xor(qsum, off);
  __syncthreads();
  if (lane == 0) redbuf[w] = qsum;
  __syncthreads();
  if (tid == 0) {
    float Q = redbuf[0] + redbuf[1] + redbuf[2] + redbuf[3];
    float log_norm = 0.5f * (sLR + (float)D_ * 1.8378770664093453f); // log(2*pi)
    ll[bs] = -0.5f * Q - (float)T_ * log_norm;
  }
}

// ---------------------------------------------------------------------------
// Final: nll[b] = -(logsumexp_s(ll) - log S). One wave per b.
// ---------------------------------------------------------------------------
__global__ __launch_bounds__(64) void k_lse(
    const float* __restrict__ ll, float* __restrict__ out)
{
  const int b = blockIdx.x;
  const int s = threadIdx.x;
  float v = ll[b * 64 + s];
  float m = v;
#pragma unroll
  for (int off = 32; off >= 1; off >>= 1) m = fmaxf(m, __shfl_xor(m, off));
  float e = __expf(v - m);
#pragma unroll
  for (int off = 32; off >= 1; off >>= 1) e += __shfl_xor(e, off);
  if (s == 0) out[b] = -(m + __logf(e) - 4.1588830833596715f); // log(64)
}

extern "C" void kernel_launch(void* const* d_in, const int* in_sizes, int n_in,
                              void* d_out, int out_size, void* d_ws, size_t ws_size,
                              hipStream_t stream) {
  const float* X        = (const float*)d_in[0];
  const float* times    = (const float*)d_in[1];
  const float* log_taus = (const float*)d_in[2];
  const float* log_R    = (const float*)d_in[3];
  const float* W1       = (const float*)d_in[4];
  const float* b1       = (const float*)d_in[5];
  const float* W2       = (const float*)d_in[6];
  const float* b2       = (const float*)d_in[7];
  const float* eps      = (const float*)d_in[8];
  float* out = (float*)d_out;

  char* ws = (char*)d_ws;
  float* Lc = (float*)ws;                                    // 2 MiB  [L][T][T]
  float* Z  = (float*)(ws + 2097152);                        // 16 MiB [BS][L][T]
  float* ll = (float*)(ws + 2097152 + 16777216);             // 8 KiB  [BS]
  __hip_bfloat16* W2T = (__hip_bfloat16*)(ws + 2097152 + 16777216 + 8192); // 32 KiB

  hipMemsetAsync(Lc, 0, 2097152, stream);   // upper triangle / untouched rows = 0

  hipLaunchKernelGGL(k_cholesky, dim3(8),    dim3(256), 0, stream, times, log_taus, Lc);
  hipLaunchKernelGGL(k_w2t,      dim3(64),   dim3(256), 0, stream, W2, W2T);
  hipLaunchKernelGGL(k_zgemm,    dim3(1024), dim3(256), 0, stream, eps, Lc, Z);
  hipLaunchKernelGGL(k_decode,   dim3(2048), dim3(256), 0, stream, X, Z, W1, b1, W2T, b2, log_R, ll);
  hipLaunchKernelGGL(k_lse,      dim3(32),   dim3(64),  0, stream, ll, out);
}